// Round 11
// baseline (668.432 us; speedup 1.0000x reference)
//
#include <hip/hip_runtime.h>
#include <hip/hip_cooperative_groups.h>
#include <math.h>

namespace cg = cooperative_groups;

typedef float f32x4 __attribute__((ext_vector_type(4)));
typedef float f32x2 __attribute__((ext_vector_type(2)));
typedef __bf16 bf16x8 __attribute__((ext_vector_type(8)));
typedef unsigned short ushort8 __attribute__((ext_vector_type(8)));
typedef unsigned short ushort4v __attribute__((ext_vector_type(4)));

static __device__ __forceinline__ unsigned short bfbits(float f) {
    return __builtin_bit_cast(unsigned short, (__bf16)f);
}

// ---------------------------------------------------------------------------
// fe: round-7 proven kernel (FETCH ~20MB, VGPR 84, ~187us @ grid 768).
// DO NOT TOUCH CODEGEN: (256,3) bounds keep the 84-VGPR allocation;
// conv1-as-MFMA spills (r4,r8); grid 1024 was slower (r10).
// ---------------------------------------------------------------------------
__global__ __launch_bounds__(256, 3) void fe_kernel(
    const float* __restrict__ x,
    const float* __restrict__ w1T,              // [10][32]: taps 0..8 + bias row
    const float* __restrict__ w2, const float* __restrict__ b2,
    unsigned short* __restrict__ poolbf, int n)
{
    __shared__ unsigned short hT[4][100][40];
    __shared__ float xs[4][104];

    const int t = threadIdx.x, lane = t & 63, wave = t >> 6;
    const int cl = lane & 15, kg = lane >> 4;

    bf16x8 bfr[4][4];
    #pragma unroll
    for (int ct = 0; ct < 4; ++ct)
        #pragma unroll
        for (int tap = 0; tap < 4; ++tap) {
            const float* gp = w2 + (size_t)(ct * 16 + cl) * 128 + kg * 32 + tap;
            ushort8 u;
            #pragma unroll
            for (int e = 0; e < 8; ++e) u[e] = bfbits(gp[e * 4]);
            bfr[ct][tap] = __builtin_bit_cast(bf16x8, u);
        }
    float b2r[4];
    #pragma unroll
    for (int ct = 0; ct < 4; ++ct) b2r[ct] = b2[ct * 16 + cl];

    unsigned int pm[3] = {0u, 0u, 0u};
    #pragma unroll
    for (int mt = 0; mt < 6; ++mt)
        #pragma unroll
        for (int rg = 0; rg < 4; ++rg) {
            const int slot = mt * 4 + rg;
            const int pd = mt * 16 + kg * 4 + rg;
            unsigned int bits = 0;
            if (pd < 81) {
                const int id = pd / 9, jd = pd - 9 * (pd / 9);
                if (id <= 4 && jd <= 4) bits |= 1u;
                if (id <= 4 && jd >= 4) bits |= 2u;
                if (id >= 4 && jd <= 4) bits |= 4u;
                if (id >= 4 && jd >= 4) bits |= 8u;
            }
            pm[slot >> 3] |= bits << ((slot & 7) * 4);
        }

    int rbase[6];
    #pragma unroll
    for (int mt = 0; mt < 6; ++mt) {
        const int p = mt * 16 + cl;
        const int ia = p / 9, ja = p - 9 * ia;
        rbase[mt] = (p < 81) ? (ia * 10 + ja) : 0;
    }

    {
        ushort8 z8 = {0,0,0,0,0,0,0,0};
        for (int r = lane; r < 100; r += 64) {
            const int pi = r / 10, pj = r - 10 * (r / 10);
            if (pi == 0 || pi == 9 || pj == 0 || pj == 9) {
                *reinterpret_cast<ushort8*>(&hT[wave][r][0])  = z8;
                *reinterpret_cast<ushort8*>(&hT[wave][r][8])  = z8;
                *reinterpret_cast<ushort8*>(&hT[wave][r][16]) = z8;
                *reinterpret_cast<ushort8*>(&hT[wave][r][24]) = z8;
                xs[wave][r] = 0.0f;
            }
        }
    }

    const int i = lane >> 3, j = lane & 7;
    const int rr = (i + 1) * 10 + (j + 1);
    const int gw = blockIdx.x * 4 + wave;
    const int nw = gridDim.x * 4;

    float v = (gw < n) ? x[(size_t)gw * 64 + lane] : 0.0f;

    for (int node = gw; node < n; node += nw) {
        #pragma unroll
        for (int ct = 0; ct < 4; ++ct)
            #pragma unroll
            for (int tap = 0; tap < 4; ++tap) {
                f32x4 tmp = __builtin_bit_cast(f32x4, bfr[ct][tap]);
                asm volatile("" : "+v"(tmp));
                bfr[ct][tap] = __builtin_bit_cast(bf16x8, tmp);
            }

        const int nn = node + nw;
        const float vnext = x[(size_t)(nn < n ? nn : node) * 64 + lane];

        xs[wave][rr] = v;
        asm volatile("s_waitcnt lgkmcnt(0)" ::: "memory");

        float xv[9];
        #pragma unroll
        for (int ki = 0; ki < 3; ++ki)
            #pragma unroll
            for (int kj = 0; kj < 3; ++kj)
                xv[ki * 3 + kj] = xs[wave][(i + ki) * 10 + (j + kj)];

        #pragma unroll
        for (int cp = 0; cp < 4; ++cp) {
            ushort8 hv;
            #pragma unroll
            for (int half = 0; half < 2; ++half) {
                const int cg2 = cp * 2 + half;
                f32x4 s = *reinterpret_cast<const f32x4*>(w1T + 288 + cg2 * 4);
                #pragma unroll
                for (int q = 0; q < 9; ++q) {
                    const f32x4 wq = *reinterpret_cast<const f32x4*>(w1T + q * 32 + cg2 * 4);
                    s += xv[q] * wq;
                }
                #pragma unroll
                for (int c = 0; c < 4; ++c)
                    hv[half * 4 + c] = bfbits(fmaxf(s[c], 0.0f));
            }
            *reinterpret_cast<ushort8*>(&hT[wave][rr][cp * 8]) = hv;
        }
        asm volatile("s_waitcnt lgkmcnt(0)" ::: "memory");

        f32x2 pb01[4], pb23[4];
        #pragma unroll
        for (int ct = 0; ct < 4; ++ct) { pb01[ct] = (f32x2){0.f,0.f}; pb23[ct] = (f32x2){0.f,0.f}; }

        #pragma unroll
        for (int mt = 0; mt < 6; ++mt) {
            const int rb = rbase[mt];
            bf16x8 a[4];
            a[0] = *reinterpret_cast<const bf16x8*>(&hT[wave][rb][kg * 8]);
            a[1] = *reinterpret_cast<const bf16x8*>(&hT[wave][rb + 1][kg * 8]);
            a[2] = *reinterpret_cast<const bf16x8*>(&hT[wave][rb + 10][kg * 8]);
            a[3] = *reinterpret_cast<const bf16x8*>(&hT[wave][rb + 11][kg * 8]);

            f32x4 acc[4];
            #pragma unroll
            for (int ct = 0; ct < 4; ++ct)
                acc[ct] = (f32x4){b2r[ct], b2r[ct], b2r[ct], b2r[ct]};
            #pragma unroll
            for (int tap = 0; tap < 4; ++tap)
                #pragma unroll
                for (int ct = 0; ct < 4; ++ct)
                    acc[ct] = __builtin_amdgcn_mfma_f32_16x16x32_bf16(a[tap], bfr[ct][tap], acc[ct], 0, 0, 0);

            #pragma unroll
            for (int rg = 0; rg < 4; ++rg) {
                if (mt * 16 + rg >= 81) continue;
                const int slot = mt * 4 + rg;
                const unsigned int bits = pm[slot >> 3] >> ((slot & 7) * 4);
                const f32x2 w01 = {(float)(bits & 1u), (float)((bits >> 1) & 1u)};
                const f32x2 w23 = {(float)((bits >> 2) & 1u), (float)((bits >> 3) & 1u)};
                #pragma unroll
                for (int ct = 0; ct < 4; ++ct) {
                    const float vr = fmaxf(acc[ct][rg], 0.0f);
                    const f32x2 v2 = {vr, vr};
                    pb01[ct] += v2 * w01;
                    pb23[ct] += v2 * w23;
                }
            }
        }

        const bool k0 = (kg & 1) != 0;
        const bool k1 = (kg & 2) != 0;
        float outb[4];
        #pragma unroll
        for (int b = 0; b < 4; ++b) {
            const float x0 = (b < 2) ? pb01[0][b] : pb23[0][b - 2];
            const float x1 = (b < 2) ? pb01[1][b] : pb23[1][b - 2];
            const float x2 = (b < 2) ? pb01[2][b] : pb23[2][b - 2];
            const float x3 = (b < 2) ? pb01[3][b] : pb23[3][b - 2];
            float keepA = k0 ? x1 : x0, sendA = k0 ? x0 : x1;
            float keepB = k0 ? x3 : x2, sendB = k0 ? x2 : x3;
            keepA += __shfl_xor(sendA, 16);
            keepB += __shfl_xor(sendB, 16);
            float keep = k1 ? keepB : keepA, send = k1 ? keepA : keepB;
            keep += __shfl_xor(send, 32);
            outb[b] = keep;
        }
        ushort4v pv;
        #pragma unroll
        for (int b = 0; b < 4; ++b) pv[b] = bfbits(outb[b]);
        *reinterpret_cast<ushort4v*>(poolbf + (size_t)node * 256 + lane * 4) = pv;

        v = vnext;
    }
}

// ---------------------------------------------------------------------------
// precount: blocks [0,80) = weight precompute; blocks [80,..) = degree count.
// ---------------------------------------------------------------------------
__global__ void precount_k(const float* __restrict__ fw, const float* __restrict__ fb,
                           const float* __restrict__ g1w, const float* __restrict__ g2w,
                           const float* __restrict__ w1, const float* __restrict__ b1,
                           unsigned short* __restrict__ W1t, float* __restrict__ v1,
                           unsigned short* __restrict__ W2t, float* __restrict__ w1T,
                           const int* __restrict__ ei, float* __restrict__ outdeg,
                           float* __restrict__ indeg, int m)
{
    const int b = blockIdx.x, t = threadIdx.x;
    if (b < 64) {
        float s = 0.0f;
        for (int jj = 0; jj < 32; ++jj) s += fw[t * 32 + jj] * g1w[jj * 64 + b];
        W1t[b * 256 + t] = bfbits(0.04f * s);
    } else if (b < 80) {
        const int idx = (b - 64) * 256 + t;
        const int nc = idx >> 6, k = idx & 63;
        W2t[nc * 64 + k] = bfbits(g2w[k * 64 + nc]);
        if (b == 64 && t < 64) {
            float s = 0.0f;
            for (int jj = 0; jj < 32; ++jj) s += fb[jj] * g1w[jj * 64 + t];
            v1[t] = s;
        }
        if (b == 65 && t < 320) {
            const int q = t >> 5, c = t & 31;
            w1T[t] = (q < 9) ? w1[c * 9 + q] : b1[c];
        }
    } else {
        const int e = (b - 80) * 256 + t;
        if (e >= m) return;
        atomicAdd(&outdeg[ei[e]], 1.0f);
        atomicAdd(&indeg[ei[m + e]], 1.0f);
    }
}

// ---------------------------------------------------------------------------
// Fused tail: one cooperative kernel, 7 phases separated by grid.sync().
// Fallback: same kernel launched per-phase (phase >= 0) on the stream.
// ---------------------------------------------------------------------------
struct TailArgs {
    const unsigned short* poolbf;
    const unsigned short* W1t;
    const float* v1;
    float* h;
    float* acc;
    const float* aux;
    const int* ei;
    const float* outdeg;
    const float* indeg;
    float* dis;
    float* att1;
    float* att2;
    const float* g1b;
    const unsigned short* W2t;
    const float* g2b;
    const float* fcw;
    const float* fcb;
    const float* outw;
    const float* outb;
    float* out;
    int n, m;
};

__device__ __forceinline__ void phase_attprep(const TailArgs& a)
{
    const int nm = a.n > a.m ? a.n : a.m;
    const int stride = gridDim.x * 256;
    for (int e = blockIdx.x * 256 + threadIdx.x; e < nm; e += stride) {
        if (e < a.n) a.dis[e] = rsqrtf(a.indeg[e] + 1.0f);
        if (e < a.m) {
            const int s = a.ei[e], d = a.ei[a.m + e];
            const float fs = a.aux[(size_t)s * 3 + 2], fdd = a.aux[(size_t)d * 3 + 2];
            const float fd = fabsf(fs - fdd);
            a.att1[e] = (fd == 1.0f) ? (1.0f / fmaxf(a.outdeg[s], 1.0f)) : 0.0f;
            const float angs = a.aux[(size_t)s * 3 + 0], rads = a.aux[(size_t)s * 3 + 1];
            const float angd = a.aux[(size_t)d * 3 + 0], radd = a.aux[(size_t)d * 3 + 1];
            const float dx = radd * cosf(angd) - rads * cosf(angs);
            const float dy = radd * sinf(angd) - rads * sinf(angs);
            const float vel = sqrtf(dx * dx + dy * dy + 1e-12f) * 0.5f;
            a.att2[e] = (fd == 2.0f) ? expf(-vel / 8.5f) : 0.0f;
        }
    }
}

__device__ __forceinline__ void phase_mm1(const TailArgs& a)
{
    const int t = threadIdx.x, lane = t & 63;
    const int cl = lane & 15, kg = lane >> 4;
    const int gw = blockIdx.x * 4 + (t >> 6);
    const int nw = gridDim.x * 4;
    const int ntiles = (a.n + 15) >> 4;

    float vv[4];
    #pragma unroll
    for (int nt = 0; nt < 4; ++nt) vv[nt] = a.v1[nt * 16 + cl];

    for (int mt = gw; mt < ntiles; mt += nw) {
        const int r = min(mt * 16 + cl, a.n - 1);
        const unsigned short* ar = a.poolbf + (size_t)r * 256 + kg * 8;
        f32x4 accf[4];
        #pragma unroll
        for (int nt = 0; nt < 4; ++nt)
            accf[nt] = (f32x4){vv[nt], vv[nt], vv[nt], vv[nt]};
        #pragma unroll
        for (int ks = 0; ks < 8; ++ks) {
            const bf16x8 afr = *reinterpret_cast<const bf16x8*>(ar + ks * 32);
            #pragma unroll
            for (int nt = 0; nt < 4; ++nt) {
                const bf16x8 bfrg = *reinterpret_cast<const bf16x8*>(
                    a.W1t + (size_t)(nt * 16 + cl) * 256 + ks * 32 + kg * 8);
                accf[nt] = __builtin_amdgcn_mfma_f32_16x16x32_bf16(afr, bfrg, accf[nt], 0, 0, 0);
            }
        }
        #pragma unroll
        for (int nt = 0; nt < 4; ++nt)
            #pragma unroll
            for (int rg = 0; rg < 4; ++rg) {
                const int row = mt * 16 + (kg << 2) + rg;
                if (row < a.n) a.h[(size_t)row * 64 + nt * 16 + cl] = accf[nt][rg];
            }
    }
}

__device__ __forceinline__ void phase_zacc(const TailArgs& a)
{
    const size_t total = (size_t)a.n * 16;   // f32x4 units
    f32x4* p = reinterpret_cast<f32x4*>(a.acc);
    const size_t stride = (size_t)gridDim.x * 256;
    const f32x4 z = {0.f, 0.f, 0.f, 0.f};
    for (size_t q = (size_t)blockIdx.x * 256 + threadIdx.x; q < total; q += stride)
        p[q] = z;
}

template<bool HAS_S>
__device__ __forceinline__ void phase_scatter(const TailArgs& a)
{
    const float* skd = HAS_S ? a.att2 : a.att1;
    const size_t total = (size_t)a.m * 64;
    const size_t stride = (size_t)gridDim.x * 256;
    for (size_t idx = (size_t)blockIdx.x * 256 + threadIdx.x; idx < total; idx += stride) {
        const int e = (int)(idx >> 6), k = (int)(idx & 63);
        const int s = a.ei[e], d = a.ei[a.m + e];
        if (skd[d] == 0.0f) continue;
        if (HAS_S && a.att1[s] == 0.0f) continue;
        const float w = a.dis[s] * a.dis[d];
        atomicAdd(&a.acc[(size_t)d * 64 + k], w * a.h[(size_t)s * 64 + k]);
    }
}

__device__ __forceinline__ void phase_mm2f(const TailArgs& a)
{
    const int t = threadIdx.x, lane = t & 63;
    const int cl = lane & 15, kg = lane >> 4;
    const int gw = blockIdx.x * 4 + (t >> 6);
    const int nw = gridDim.x * 4;
    const int ntiles = (a.n + 15) >> 4;

    for (int mt = gw; mt < ntiles; mt += nw) {
        const int r = min(mt * 16 + cl, a.n - 1);
        const float di = a.dis[r];
        const float di2 = di * di;
        const float at = a.att1[r];
        f32x4 accf[4];
        #pragma unroll
        for (int nt = 0; nt < 4; ++nt) accf[nt] = (f32x4){0.f, 0.f, 0.f, 0.f};
        #pragma unroll
        for (int ks = 0; ks < 2; ++ks) {
            const float* ap = a.acc + (size_t)r * 64 + ks * 32 + kg * 8;
            const float* hp = a.h   + (size_t)r * 64 + ks * 32 + kg * 8;
            const float* bp = a.g1b + ks * 32 + kg * 8;
            ushort8 u;
            #pragma unroll
            for (int e = 0; e < 8; ++e)
                u[e] = bfbits(fmaxf((ap[e] + bp[e] + di2 * hp[e]) * at, 0.0f));
            {   // zero acc rows for scatter2 (each row touched by exactly one lane-group)
                const f32x4 z = {0.f, 0.f, 0.f, 0.f};
                float* zp = a.acc + (size_t)r * 64 + ks * 32 + kg * 8;
                *reinterpret_cast<f32x4*>(zp)     = z;
                *reinterpret_cast<f32x4*>(zp + 4) = z;
            }
            const bf16x8 afr = __builtin_bit_cast(bf16x8, u);
            #pragma unroll
            for (int nt = 0; nt < 4; ++nt) {
                const bf16x8 bfrg = *reinterpret_cast<const bf16x8*>(
                    a.W2t + (size_t)(nt * 16 + cl) * 64 + ks * 32 + kg * 8);
                accf[nt] = __builtin_amdgcn_mfma_f32_16x16x32_bf16(afr, bfrg, accf[nt], 0, 0, 0);
            }
        }
        #pragma unroll
        for (int nt = 0; nt < 4; ++nt)
            #pragma unroll
            for (int rg = 0; rg < 4; ++rg) {
                const int row = mt * 16 + (kg << 2) + rg;
                if (row < a.n) a.h[(size_t)row * 64 + nt * 16 + cl] = accf[nt][rg];
            }
    }
}

__device__ __forceinline__ void phase_finhead(const TailArgs& a)
{
    __shared__ float sm[8][64];
    const int t = threadIdx.x;

    for (int nb = blockIdx.x * 8; nb < a.n; nb += gridDim.x * 8) {
        #pragma unroll
        for (int pp = 0; pp < 2; ++pp) {
            const int p = t + pp * 256;
            const int nd = p >> 6, k = p & 63;
            const int node = nb + nd;
            if (node < a.n) {
                const float di = a.dis[node];
                const size_t idx = (size_t)node * 64 + k;
                sm[nd][k] = fmaxf((a.acc[idx] + a.g2b[k] + di * di * a.h[idx]) * a.att2[node], 0.0f);
            }
        }
        __syncthreads();

        const int nd = t >> 5, o = t & 31;
        const int node = nb + nd;
        if (node < a.n) {
            float s = a.fcb[o];
            #pragma unroll
            for (int k = 0; k < 64; ++k) s = fmaf(sm[nd][k], a.fcw[k * 32 + o], s);
            s = fmaxf(s, 0.0f);
            float p = s * a.outw[o];
            #pragma unroll
            for (int mk = 16; mk >= 1; mk >>= 1) p += __shfl_xor(p, mk);
            if (o == 0) a.out[node] = 1.0f / (1.0f + expf(-(p + a.outb[0])));
        }
        __syncthreads();   // before next iteration overwrites sm
    }
}

__global__ __launch_bounds__(256, 4) void tail_k(TailArgs a, int phase)
{
    if (phase < 0) {
        cg::grid_group g = cg::this_grid();
        phase_attprep(a);        g.sync();
        phase_mm1(a);            g.sync();
        phase_zacc(a);           g.sync();
        phase_scatter<false>(a); g.sync();
        phase_mm2f(a);           g.sync();
        phase_scatter<true>(a);  g.sync();
        phase_finhead(a);
        return;
    }
    switch (phase) {
        case 0: phase_attprep(a);        break;
        case 1: phase_mm1(a);            break;
        case 2: phase_zacc(a);           break;
        case 3: phase_scatter<false>(a); break;
        case 4: phase_mm2f(a);           break;
        case 5: phase_scatter<true>(a);  break;
        case 6: phase_finhead(a);        break;
    }
}

// ---------------------------------------------------------------------------
extern "C" void kernel_launch(void* const* d_in, const int* in_sizes, int n_in,
                              void* d_out, int out_size, void* d_ws, size_t ws_size,
                              hipStream_t stream)
{
    const float* x    = (const float*)d_in[0];
    const float* aux  = (const float*)d_in[1];
    const int*   ei   = (const int*)  d_in[2];
    const float* c1w  = (const float*)d_in[3];
    const float* c1b  = (const float*)d_in[4];
    const float* c2w  = (const float*)d_in[5];
    const float* c2b  = (const float*)d_in[6];
    const float* few  = (const float*)d_in[7];
    const float* feb  = (const float*)d_in[8];
    const float* g1w  = (const float*)d_in[9];
    const float* g1b  = (const float*)d_in[10];
    const float* g2w  = (const float*)d_in[11];
    const float* g2b  = (const float*)d_in[12];
    const float* fcw  = (const float*)d_in[13];
    const float* fcb  = (const float*)d_in[14];
    const float* outw = (const float*)d_in[15];
    const float* outb = (const float*)d_in[16];
    float* out = (float*)d_out;

    const int n = in_sizes[0] / 64;       // nodes
    const int m = in_sizes[2] / 2;        // edges

    // overlay layout (r7): acc overlays poolbf; safe because zacc is a
    // separate phase AFTER mm1 fully consumes poolbf.
    float* ws = (float*)d_ws;
    unsigned short* poolbf = (unsigned short*)ws;            // n*256 bf16
    float* acc  = ws;                                        // n*64 f32 (overlay)
    float* h    = ws + (size_t)n * 128;                      // n*64 f32
    float* wtail = ws + (size_t)n * 192;
    unsigned short* W1t = (unsigned short*)wtail;            // 8192 f32
    float* v1   = wtail + 8192;                              // 64
    unsigned short* W2t = (unsigned short*)(v1 + 64);        // 2048 f32
    float* w1T    = v1 + 64 + 2048;                          // 320
    float* outdeg = w1T + 320;                               // n
    float* indeg  = outdeg + n;                              // n
    float* dis    = indeg + n;                               // n
    float* att1   = dis + n;                                 // m
    float* att2   = att1 + m;                                // m

    const dim3 b256(256);
    const int gE = (m + 255) / 256;

    hipMemsetAsync(outdeg, 0, (size_t)2 * n * sizeof(float), stream);
    precount_k<<<80 + gE, b256, 0, stream>>>(few, feb, g1w, g2w, c1w, c1b,
                                             W1t, v1, W2t, w1T, ei, outdeg, indeg, m);
    fe_kernel<<<768, b256, 0, stream>>>(x, w1T, c2w, c2b, poolbf, n);

    TailArgs ta;
    ta.poolbf = poolbf; ta.W1t = W1t; ta.v1 = v1; ta.h = h; ta.acc = acc;
    ta.aux = aux; ta.ei = ei; ta.outdeg = outdeg; ta.indeg = indeg;
    ta.dis = dis; ta.att1 = att1; ta.att2 = att2; ta.g1b = g1b; ta.W2t = W2t;
    ta.g2b = g2b; ta.fcw = fcw; ta.fcb = fcb; ta.outw = outw; ta.outb = outb;
    ta.out = out; ta.n = n; ta.m = m;

    bool done = false;
    int dev = 0;
    hipGetDevice(&dev);
    int coop = 0;
    hipDeviceGetAttribute(&coop, hipDeviceAttributeCooperativeLaunch, dev);
    if (coop) {
        int nCU = 0;
        hipDeviceGetAttribute(&nCU, hipDeviceAttributeMultiprocessorCount, dev);
        int maxb = 0;
        hipError_t occ = hipOccupancyMaxActiveBlocksPerMultiprocessor(
            &maxb, reinterpret_cast<const void*>(tail_k), 256, 0);
        if (occ == hipSuccess && maxb > 0 && nCU > 0) {
            int grid = maxb * nCU;
            if (grid > 2048) grid = 2048;
            int ph = -1;
            void* args[] = { &ta, &ph };
            if (hipLaunchCooperativeKernel(reinterpret_cast<const void*>(tail_k),
                                           dim3(grid), dim3(256), args, 0, stream) == hipSuccess)
                done = true;
        }
    }
    if (!done) {
        for (int ph = 0; ph < 7; ++ph)
            tail_k<<<1024, b256, 0, stream>>>(ta, ph);
    }
}

// Round 12
// 252.561 us; speedup vs baseline: 2.6466x; 2.6466x over previous
//
#include <hip/hip_runtime.h>
#include <math.h>

typedef float f32x4 __attribute__((ext_vector_type(4)));
typedef float f32x2 __attribute__((ext_vector_type(2)));
typedef __bf16 bf16x8 __attribute__((ext_vector_type(8)));
typedef unsigned short ushort8 __attribute__((ext_vector_type(8)));
typedef unsigned short ushort4v __attribute__((ext_vector_type(4)));

static __device__ __forceinline__ unsigned short bfbits(float f) {
    return __builtin_bit_cast(unsigned short, (__bf16)f);
}

// ---------------------------------------------------------------------------
// fe: round-7 proven kernel (FETCH ~20MB, VGPR 84, ~186us @ grid 768).
// DO NOT TOUCH CODEGEN: (256,3) bounds keep the 84-VGPR allocation;
// conv1-as-MFMA spills (r4,r8); grid 1024 slower (r10); coop tail 3x worse (r11).
// ---------------------------------------------------------------------------
__global__ __launch_bounds__(256, 3) void fe_kernel(
    const float* __restrict__ x,
    const float* __restrict__ w1T,              // [10][32]: taps 0..8 + bias row
    const float* __restrict__ w2, const float* __restrict__ b2,
    unsigned short* __restrict__ poolbf, int n)
{
    __shared__ unsigned short hT[4][100][40];     // per-wave padded 10x10 x 32ci bf16
    __shared__ float xs[4][104];                  // per-wave padded input

    const int t = threadIdx.x, lane = t & 63, wave = t >> 6;
    const int cl = lane & 15, kg = lane >> 4;

    bf16x8 bfr[4][4];
    #pragma unroll
    for (int ct = 0; ct < 4; ++ct)
        #pragma unroll
        for (int tap = 0; tap < 4; ++tap) {
            const float* gp = w2 + (size_t)(ct * 16 + cl) * 128 + kg * 32 + tap;
            ushort8 u;
            #pragma unroll
            for (int e = 0; e < 8; ++e) u[e] = bfbits(gp[e * 4]);
            bfr[ct][tap] = __builtin_bit_cast(bf16x8, u);
        }
    float b2r[4];
    #pragma unroll
    for (int ct = 0; ct < 4; ++ct) b2r[ct] = b2[ct * 16 + cl];

    unsigned int pm[3] = {0u, 0u, 0u};
    #pragma unroll
    for (int mt = 0; mt < 6; ++mt)
        #pragma unroll
        for (int rg = 0; rg < 4; ++rg) {
            const int slot = mt * 4 + rg;
            const int pd = mt * 16 + kg * 4 + rg;
            unsigned int bits = 0;
            if (pd < 81) {
                const int id = pd / 9, jd = pd - 9 * (pd / 9);
                if (id <= 4 && jd <= 4) bits |= 1u;
                if (id <= 4 && jd >= 4) bits |= 2u;
                if (id >= 4 && jd <= 4) bits |= 4u;
                if (id >= 4 && jd >= 4) bits |= 8u;
            }
            pm[slot >> 3] |= bits << ((slot & 7) * 4);
        }

    int rbase[6];
    #pragma unroll
    for (int mt = 0; mt < 6; ++mt) {
        const int p = mt * 16 + cl;
        const int ia = p / 9, ja = p - 9 * ia;
        rbase[mt] = (p < 81) ? (ia * 10 + ja) : 0;
    }

    {
        ushort8 z8 = {0,0,0,0,0,0,0,0};
        for (int r = lane; r < 100; r += 64) {
            const int pi = r / 10, pj = r - 10 * (r / 10);
            if (pi == 0 || pi == 9 || pj == 0 || pj == 9) {
                *reinterpret_cast<ushort8*>(&hT[wave][r][0])  = z8;
                *reinterpret_cast<ushort8*>(&hT[wave][r][8])  = z8;
                *reinterpret_cast<ushort8*>(&hT[wave][r][16]) = z8;
                *reinterpret_cast<ushort8*>(&hT[wave][r][24]) = z8;
                xs[wave][r] = 0.0f;
            }
        }
    }

    const int i = lane >> 3, j = lane & 7;
    const int rr = (i + 1) * 10 + (j + 1);
    const int gw = blockIdx.x * 4 + wave;
    const int nw = gridDim.x * 4;

    float v = (gw < n) ? x[(size_t)gw * 64 + lane] : 0.0f;

    for (int node = gw; node < n; node += nw) {
        #pragma unroll
        for (int ct = 0; ct < 4; ++ct)
            #pragma unroll
            for (int tap = 0; tap < 4; ++tap) {
                f32x4 tmp = __builtin_bit_cast(f32x4, bfr[ct][tap]);
                asm volatile("" : "+v"(tmp));
                bfr[ct][tap] = __builtin_bit_cast(bf16x8, tmp);
            }

        const int nn = node + nw;
        const float vnext = x[(size_t)(nn < n ? nn : node) * 64 + lane];

        xs[wave][rr] = v;
        asm volatile("s_waitcnt lgkmcnt(0)" ::: "memory");

        float xv[9];
        #pragma unroll
        for (int ki = 0; ki < 3; ++ki)
            #pragma unroll
            for (int kj = 0; kj < 3; ++kj)
                xv[ki * 3 + kj] = xs[wave][(i + ki) * 10 + (j + kj)];

        #pragma unroll
        for (int cp = 0; cp < 4; ++cp) {
            ushort8 hv;
            #pragma unroll
            for (int half = 0; half < 2; ++half) {
                const int cg2 = cp * 2 + half;
                f32x4 s = *reinterpret_cast<const f32x4*>(w1T + 288 + cg2 * 4);
                #pragma unroll
                for (int q = 0; q < 9; ++q) {
                    const f32x4 wq = *reinterpret_cast<const f32x4*>(w1T + q * 32 + cg2 * 4);
                    s += xv[q] * wq;
                }
                #pragma unroll
                for (int c = 0; c < 4; ++c)
                    hv[half * 4 + c] = bfbits(fmaxf(s[c], 0.0f));
            }
            *reinterpret_cast<ushort8*>(&hT[wave][rr][cp * 8]) = hv;
        }
        asm volatile("s_waitcnt lgkmcnt(0)" ::: "memory");

        f32x2 pb01[4], pb23[4];
        #pragma unroll
        for (int ct = 0; ct < 4; ++ct) { pb01[ct] = (f32x2){0.f,0.f}; pb23[ct] = (f32x2){0.f,0.f}; }

        #pragma unroll
        for (int mt = 0; mt < 6; ++mt) {
            const int rb = rbase[mt];
            bf16x8 a[4];
            a[0] = *reinterpret_cast<const bf16x8*>(&hT[wave][rb][kg * 8]);
            a[1] = *reinterpret_cast<const bf16x8*>(&hT[wave][rb + 1][kg * 8]);
            a[2] = *reinterpret_cast<const bf16x8*>(&hT[wave][rb + 10][kg * 8]);
            a[3] = *reinterpret_cast<const bf16x8*>(&hT[wave][rb + 11][kg * 8]);

            f32x4 acc[4];
            #pragma unroll
            for (int ct = 0; ct < 4; ++ct)
                acc[ct] = (f32x4){b2r[ct], b2r[ct], b2r[ct], b2r[ct]};
            #pragma unroll
            for (int tap = 0; tap < 4; ++tap)
                #pragma unroll
                for (int ct = 0; ct < 4; ++ct)
                    acc[ct] = __builtin_amdgcn_mfma_f32_16x16x32_bf16(a[tap], bfr[ct][tap], acc[ct], 0, 0, 0);

            #pragma unroll
            for (int rg = 0; rg < 4; ++rg) {
                if (mt * 16 + rg >= 81) continue;
                const int slot = mt * 4 + rg;
                const unsigned int bits = pm[slot >> 3] >> ((slot & 7) * 4);
                const f32x2 w01 = {(float)(bits & 1u), (float)((bits >> 1) & 1u)};
                const f32x2 w23 = {(float)((bits >> 2) & 1u), (float)((bits >> 3) & 1u)};
                #pragma unroll
                for (int ct = 0; ct < 4; ++ct) {
                    const float vr = fmaxf(acc[ct][rg], 0.0f);
                    const f32x2 v2 = {vr, vr};
                    pb01[ct] += v2 * w01;
                    pb23[ct] += v2 * w23;
                }
            }
        }

        const bool k0 = (kg & 1) != 0;
        const bool k1 = (kg & 2) != 0;
        float outb[4];
        #pragma unroll
        for (int b = 0; b < 4; ++b) {
            const float x0 = (b < 2) ? pb01[0][b] : pb23[0][b - 2];
            const float x1 = (b < 2) ? pb01[1][b] : pb23[1][b - 2];
            const float x2 = (b < 2) ? pb01[2][b] : pb23[2][b - 2];
            const float x3 = (b < 2) ? pb01[3][b] : pb23[3][b - 2];
            float keepA = k0 ? x1 : x0, sendA = k0 ? x0 : x1;
            float keepB = k0 ? x3 : x2, sendB = k0 ? x2 : x3;
            keepA += __shfl_xor(sendA, 16);
            keepB += __shfl_xor(sendB, 16);
            float keep = k1 ? keepB : keepA, send = k1 ? keepA : keepB;
            keep += __shfl_xor(send, 32);
            outb[b] = keep;
        }
        ushort4v pv;
        #pragma unroll
        for (int b = 0; b < 4; ++b) pv[b] = bfbits(outb[b]);
        *reinterpret_cast<ushort4v*>(poolbf + (size_t)node * 256 + lane * 4) = pv;

        v = vnext;
    }
}

// ---------------------------------------------------------------------------
// precount: blocks [0,80) = weight precompute; blocks [80,..) = degree count.
// ---------------------------------------------------------------------------
__global__ void precount_k(const float* __restrict__ fw, const float* __restrict__ fb,
                           const float* __restrict__ g1w, const float* __restrict__ g2w,
                           const float* __restrict__ w1, const float* __restrict__ b1,
                           unsigned short* __restrict__ W1t, float* __restrict__ v1,
                           unsigned short* __restrict__ W2t, float* __restrict__ w1T,
                           const int* __restrict__ ei, float* __restrict__ outdeg,
                           float* __restrict__ indeg, int m)
{
    const int b = blockIdx.x, t = threadIdx.x;
    if (b < 64) {
        float s = 0.0f;
        for (int jj = 0; jj < 32; ++jj) s += fw[t * 32 + jj] * g1w[jj * 64 + b];
        W1t[b * 256 + t] = bfbits(0.04f * s);
    } else if (b < 80) {
        const int idx = (b - 64) * 256 + t;
        const int nc = idx >> 6, k = idx & 63;
        W2t[nc * 64 + k] = bfbits(g2w[k * 64 + nc]);
        if (b == 64 && t < 64) {
            float s = 0.0f;
            for (int jj = 0; jj < 32; ++jj) s += fb[jj] * g1w[jj * 64 + t];
            v1[t] = s;
        }
        if (b == 65 && t < 320) {
            const int q = t >> 5, c = t & 31;
            w1T[t] = (q < 9) ? w1[c * 9 + q] : b1[c];
        }
    } else {
        const int e = (b - 80) * 256 + t;
        if (e >= m) return;
        atomicAdd(&outdeg[ei[e]], 1.0f);
        atomicAdd(&indeg[ei[m + e]], 1.0f);
    }
}

// ---------------------------------------------------------------------------
// mm1att: blocks [0,gmm) = h = pool @ W1t (+v1), zero acc rows when separate;
//         blocks [gmm,..) = attprep (dis + att1 + att2).
// ---------------------------------------------------------------------------
template<bool ZEROACC>
__global__ __launch_bounds__(256) void mm1att_k(
    const unsigned short* __restrict__ A, const unsigned short* __restrict__ Bt,
    const float* __restrict__ v1, float* __restrict__ h, float* __restrict__ acc,
    const float* __restrict__ aux, const int* __restrict__ ei,
    const float* __restrict__ outdeg, const float* __restrict__ indeg,
    float* __restrict__ dis, float* __restrict__ att1, float* __restrict__ att2,
    int n, int m, int gmm)
{
    const int t = threadIdx.x;
    if ((int)blockIdx.x >= gmm) {
        const int e = (blockIdx.x - gmm) * 256 + t;
        if (e < n) dis[e] = rsqrtf(indeg[e] + 1.0f);
        if (e >= m) return;
        const int s = ei[e], d = ei[m + e];
        const float fs = aux[(size_t)s * 3 + 2], fdd = aux[(size_t)d * 3 + 2];
        const float fd = fabsf(fs - fdd);
        att1[e] = (fd == 1.0f) ? (1.0f / fmaxf(outdeg[s], 1.0f)) : 0.0f;
        const float angs = aux[(size_t)s * 3 + 0], rads = aux[(size_t)s * 3 + 1];
        const float angd = aux[(size_t)d * 3 + 0], radd = aux[(size_t)d * 3 + 1];
        const float dx = radd * cosf(angd) - rads * cosf(angs);
        const float dy = radd * sinf(angd) - rads * sinf(angs);
        const float vel = sqrtf(dx * dx + dy * dy + 1e-12f) * 0.5f;
        att2[e] = (fd == 2.0f) ? expf(-vel / 8.5f) : 0.0f;
        return;
    }

    const int lane = t & 63;
    const int cl = lane & 15, kg = lane >> 4;
    const int gw = blockIdx.x * 4 + (t >> 6);
    const int nw = gmm * 4;
    const int ntiles = (n + 15) >> 4;

    float vv[4];
    #pragma unroll
    for (int nt = 0; nt < 4; ++nt) vv[nt] = v1[nt * 16 + cl];

    for (int mt = gw; mt < ntiles; mt += nw) {
        const int r = min(mt * 16 + cl, n - 1);
        const unsigned short* ar = A + (size_t)r * 256 + kg * 8;
        f32x4 accf[4];
        #pragma unroll
        for (int nt = 0; nt < 4; ++nt)
            accf[nt] = (f32x4){vv[nt], vv[nt], vv[nt], vv[nt]};
        #pragma unroll
        for (int ks = 0; ks < 8; ++ks) {
            const bf16x8 afr = *reinterpret_cast<const bf16x8*>(ar + ks * 32);
            #pragma unroll
            for (int nt = 0; nt < 4; ++nt) {
                const bf16x8 bfrg = *reinterpret_cast<const bf16x8*>(
                    Bt + (size_t)(nt * 16 + cl) * 256 + ks * 32 + kg * 8);
                accf[nt] = __builtin_amdgcn_mfma_f32_16x16x32_bf16(afr, bfrg, accf[nt], 0, 0, 0);
            }
        }
        #pragma unroll
        for (int nt = 0; nt < 4; ++nt)
            #pragma unroll
            for (int rg = 0; rg < 4; ++rg) {
                const int row = mt * 16 + (kg << 2) + rg;
                if (row < n) h[(size_t)row * 64 + nt * 16 + cl] = accf[nt][rg];
            }
        if (ZEROACC) {
            const int zr = mt * 16 + cl;
            if (zr < n) {
                const f32x4 z = {0.f, 0.f, 0.f, 0.f};
                float* zp = acc + (size_t)zr * 64 + kg * 16;
                *reinterpret_cast<f32x4*>(zp)      = z;
                *reinterpret_cast<f32x4*>(zp + 4)  = z;
                *reinterpret_cast<f32x4*>(zp + 8)  = z;
                *reinterpret_cast<f32x4*>(zp + 12) = z;
            }
        }
    }
}

// ---------------------------------------------------------------------------
// mm2f: fused fin1 + GCN-2 matmul; zeroes acc rows after reading them.
// ---------------------------------------------------------------------------
template<bool ZEROACC>
__global__ __launch_bounds__(256) void mm2f_k(
    const float* __restrict__ acc, const float* __restrict__ hin,
    const float* __restrict__ dis, const float* __restrict__ g1b,
    const float* __restrict__ att1, const unsigned short* __restrict__ Bt,
    float* __restrict__ hout, float* __restrict__ accz, int n)
{
    const int lane = threadIdx.x & 63;
    const int cl = lane & 15, kg = lane >> 4;
    const int gw = blockIdx.x * 4 + (threadIdx.x >> 6);
    const int nw = gridDim.x * 4;
    const int ntiles = (n + 15) >> 4;

    for (int mt = gw; mt < ntiles; mt += nw) {
        const int r = min(mt * 16 + cl, n - 1);
        const float di = dis[r];
        const float di2 = di * di;
        const float at = att1[r];
        f32x4 accf[4];
        #pragma unroll
        for (int nt = 0; nt < 4; ++nt) accf[nt] = (f32x4){0.f, 0.f, 0.f, 0.f};
        #pragma unroll
        for (int ks = 0; ks < 2; ++ks) {
            const float* ap = acc + (size_t)r * 64 + ks * 32 + kg * 8;
            const float* hp = hin + (size_t)r * 64 + ks * 32 + kg * 8;
            const float* bp = g1b + ks * 32 + kg * 8;
            ushort8 u;
            #pragma unroll
            for (int e = 0; e < 8; ++e)
                u[e] = bfbits(fmaxf((ap[e] + bp[e] + di2 * hp[e]) * at, 0.0f));
            if (ZEROACC) {
                const f32x4 z = {0.f, 0.f, 0.f, 0.f};
                float* zp = accz + (size_t)r * 64 + ks * 32 + kg * 8;
                *reinterpret_cast<f32x4*>(zp)     = z;
                *reinterpret_cast<f32x4*>(zp + 4) = z;
            }
            const bf16x8 afr = __builtin_bit_cast(bf16x8, u);
            #pragma unroll
            for (int nt = 0; nt < 4; ++nt) {
                const bf16x8 bfrg = *reinterpret_cast<const bf16x8*>(
                    Bt + (size_t)(nt * 16 + cl) * 64 + ks * 32 + kg * 8);
                accf[nt] = __builtin_amdgcn_mfma_f32_16x16x32_bf16(afr, bfrg, accf[nt], 0, 0, 0);
            }
        }
        #pragma unroll
        for (int nt = 0; nt < 4; ++nt)
            #pragma unroll
            for (int rg = 0; rg < 4; ++rg) {
                const int row = mt * 16 + (kg << 2) + rg;
                if (row < n) hout[(size_t)row * 64 + nt * 16 + cl] = accf[nt][rg];
            }
    }
}

// ---------------------------------------------------------------------------
// scatter with exact-zero skip (wave-uniform early exit).
// att arrays are edge-indexed; n==m makes node-id==edge-id (reference relies
// on the same coincidence: att1[:,None] multiplies the [n,64] node matrix).
// ---------------------------------------------------------------------------
template<bool HAS_S>
__global__ void scatter_k(const float* __restrict__ h, const int* __restrict__ ei,
                          const float* __restrict__ dis,
                          const float* __restrict__ skd, const float* __restrict__ sks,
                          float* __restrict__ acc, int m)
{
    size_t idx = (size_t)blockIdx.x * blockDim.x + threadIdx.x;
    if (idx >= (size_t)m * 64) return;
    const int e = (int)(idx >> 6), k = (int)(idx & 63);
    const int s = ei[e], d = ei[m + e];
    if (skd[d] == 0.0f) return;
    if (HAS_S && sks[s] == 0.0f) return;
    const float w = dis[s] * dis[d];
    atomicAdd(&acc[(size_t)d * 64 + k], w * h[(size_t)s * 64 + k]);
}

// ---------------------------------------------------------------------------
// finhead: fin2 (relu((acc+g2b+dis^2 h)*att2)) into LDS, then head (fc+out).
// ---------------------------------------------------------------------------
__global__ __launch_bounds__(256) void finhead_k(
    const float* __restrict__ acc, const float* __restrict__ h,
    const float* __restrict__ dis, const float* __restrict__ g2b,
    const float* __restrict__ att2,
    const float* __restrict__ fcw, const float* __restrict__ fcb,
    const float* __restrict__ outw, const float* __restrict__ outb,
    float* __restrict__ out, int n)
{
    __shared__ float sm[8][64];
    const int t = threadIdx.x;
    const int nb = blockIdx.x * 8;

    #pragma unroll
    for (int pp = 0; pp < 2; ++pp) {
        const int p = t + pp * 256;
        const int nd = p >> 6, k = p & 63;
        const int node = nb + nd;
        if (node < n) {
            const float di = dis[node];
            const size_t idx = (size_t)node * 64 + k;
            sm[nd][k] = fmaxf((acc[idx] + g2b[k] + di * di * h[idx]) * att2[node], 0.0f);
        }
    }
    __syncthreads();

    const int nd = t >> 5, o = t & 31;
    const int node = nb + nd;
    if (node >= n) return;
    float s = fcb[o];
    #pragma unroll
    for (int k = 0; k < 64; ++k) s = fmaf(sm[nd][k], fcw[k * 32 + o], s);
    s = fmaxf(s, 0.0f);
    float p = s * outw[o];
    #pragma unroll
    for (int mk = 16; mk >= 1; mk >>= 1) p += __shfl_xor(p, mk);
    if (o == 0) out[node] = 1.0f / (1.0f + expf(-(p + outb[0])));
}

// ---------------------------------------------------------------------------
extern "C" void kernel_launch(void* const* d_in, const int* in_sizes, int n_in,
                              void* d_out, int out_size, void* d_ws, size_t ws_size,
                              hipStream_t stream)
{
    const float* x    = (const float*)d_in[0];
    const float* aux  = (const float*)d_in[1];
    const int*   ei   = (const int*)  d_in[2];
    const float* c1w  = (const float*)d_in[3];
    const float* c1b  = (const float*)d_in[4];
    const float* c2w  = (const float*)d_in[5];
    const float* c2b  = (const float*)d_in[6];
    const float* few  = (const float*)d_in[7];
    const float* feb  = (const float*)d_in[8];
    const float* g1w  = (const float*)d_in[9];
    const float* g1b  = (const float*)d_in[10];
    const float* g2w  = (const float*)d_in[11];
    const float* g2b  = (const float*)d_in[12];
    const float* fcw  = (const float*)d_in[13];
    const float* fcb  = (const float*)d_in[14];
    const float* outw = (const float*)d_in[15];
    const float* outb = (const float*)d_in[16];
    float* out = (float*)d_out;

    const int n = in_sizes[0] / 64;       // nodes
    const int m = in_sizes[2] / 2;        // edges

    float* ws = (float*)d_ws;
    const size_t tailf = 8192 + 64 + 2048 + 320 + (size_t)3 * n + (size_t)2 * m;
    const bool sep = ws_size >= ((size_t)n * 256 + tailf) * sizeof(float);

    unsigned short* poolbf = (unsigned short*)ws;
    float* h;
    float* acc;
    float* wtail;
    if (sep) {
        h     = ws + (size_t)n * 128;
        acc   = ws + (size_t)n * 192;
        wtail = ws + (size_t)n * 256;
    } else {
        acc   = ws;
        h     = ws + (size_t)n * 128;
        wtail = ws + (size_t)n * 192;
    }
    unsigned short* W1t = (unsigned short*)wtail;
    float* v1   = wtail + 8192;
    unsigned short* W2t = (unsigned short*)(v1 + 64);
    float* w1T    = v1 + 64 + 2048;
    float* outdeg = w1T + 320;
    float* indeg  = outdeg + n;
    float* dis    = indeg + n;
    float* att1   = dis + n;
    float* att2   = att1 + m;

    const dim3 b256(256);
    const int gE   = (m + 255) / 256;
    const int gNE  = (max(n, m) + 255) / 256;
    const int gEM  = (int)(((size_t)m * 64 + 255) / 256);
    const int gMM  = (((n + 15) / 16) + 3) / 4;

    hipMemsetAsync(outdeg, 0, (size_t)2 * n * sizeof(float), stream);
    precount_k<<<80 + gE, b256, 0, stream>>>(few, feb, g1w, g2w, c1w, c1b,
                                             W1t, v1, W2t, w1T, ei, outdeg, indeg, m);
    fe_kernel<<<768, b256, 0, stream>>>(x, w1T, c2w, c2b, poolbf, n);

    if (sep) {
        mm1att_k<true><<<gMM + gNE, b256, 0, stream>>>(poolbf, W1t, v1, h, acc,
            aux, ei, outdeg, indeg, dis, att1, att2, n, m, gMM);
    } else {
        mm1att_k<false><<<gMM + gNE, b256, 0, stream>>>(poolbf, W1t, v1, h, acc,
            aux, ei, outdeg, indeg, dis, att1, att2, n, m, gMM);
        hipMemsetAsync(acc, 0, (size_t)n * 64 * sizeof(float), stream);
    }
    // layer-1 scatter: dead if att1[dst]==0 (x1[dst] is zeroed by att1 anyway)
    scatter_k<false><<<gEM, b256, 0, stream>>>(h, ei, dis, att1, nullptr, acc, m);

    mm2f_k<true><<<gMM, b256, 0, stream>>>(acc, h, dis, g1b, att1, W2t, h, acc, n);
    // layer-2 scatter: dead if att2[dst]==0 or h2[src] row exactly zero (att1[src]==0)
    scatter_k<true><<<gEM, b256, 0, stream>>>(h, ei, dis, att2, att1, acc, m);

    finhead_k<<<(n + 7) / 8, b256, 0, stream>>>(acc, h, dis, g2b, att2,
                                                fcw, fcb, outw, outb, out, n);
}

// Round 13
// 241.747 us; speedup vs baseline: 2.7650x; 1.0447x over previous
//
#include <hip/hip_runtime.h>
#include <math.h>

typedef float f32x4 __attribute__((ext_vector_type(4)));
typedef float f32x2 __attribute__((ext_vector_type(2)));
typedef __bf16 bf16x8 __attribute__((ext_vector_type(8)));
typedef unsigned short ushort8 __attribute__((ext_vector_type(8)));
typedef unsigned short ushort4v __attribute__((ext_vector_type(4)));

static __device__ __forceinline__ unsigned short bfbits(float f) {
    return __builtin_bit_cast(unsigned short, (__bf16)f);
}

// ---------------------------------------------------------------------------
// fe: round-5 proven form (fastest measured: 182us, VGPR 84).
// conv1 fp32 VALU, weights staged ONCE in LDS (broadcast reads);
// conv2 = 96 MFMA/node with pinned B-frags. DO NOT TOUCH CODEGEN:
// (256,3) bounds keep the 84-VGPR allocation; conv1-as-MFMA spills (r4,r8);
// grid 1024 slower (r10); cooperative tail 3x worse (r11).
// ---------------------------------------------------------------------------
__global__ __launch_bounds__(256, 3) void fe_kernel(
    const float* __restrict__ x,
    const float* __restrict__ w1, const float* __restrict__ b1,
    const float* __restrict__ w2, const float* __restrict__ b2,
    unsigned short* __restrict__ poolbf, int n)
{
    __shared__ float w1t[10][32];                 // [tap 0..8 | 9=bias][c]
    __shared__ unsigned short hT[4][100][40];     // per-wave padded 10x10 x 32ci bf16
    __shared__ float xs[4][104];                  // per-wave padded input

    const int t = threadIdx.x, lane = t & 63, wave = t >> 6;
    const int cl = lane & 15, kg = lane >> 4;

    if (t < 288) w1t[t >> 5][t & 31] = w1[(t & 31) * 9 + (t >> 5)];
    if (t >= 288 && t < 320) w1t[9][t - 288] = b1[t - 288];

    bf16x8 bfr[4][4];
    #pragma unroll
    for (int ct = 0; ct < 4; ++ct)
        #pragma unroll
        for (int tap = 0; tap < 4; ++tap) {
            const float* gp = w2 + (size_t)(ct * 16 + cl) * 128 + kg * 32 + tap;
            ushort8 u;
            #pragma unroll
            for (int e = 0; e < 8; ++e) u[e] = bfbits(gp[e * 4]);
            bfr[ct][tap] = __builtin_bit_cast(bf16x8, u);
        }
    float b2r[4];
    #pragma unroll
    for (int ct = 0; ct < 4; ++ct) b2r[ct] = b2[ct * 16 + cl];

    unsigned int pm[3] = {0u, 0u, 0u};
    #pragma unroll
    for (int mt = 0; mt < 6; ++mt)
        #pragma unroll
        for (int rg = 0; rg < 4; ++rg) {
            const int slot = mt * 4 + rg;
            const int pd = mt * 16 + kg * 4 + rg;
            unsigned int bits = 0;
            if (pd < 81) {
                const int id = pd / 9, jd = pd - 9 * (pd / 9);
                if (id <= 4 && jd <= 4) bits |= 1u;
                if (id <= 4 && jd >= 4) bits |= 2u;
                if (id >= 4 && jd <= 4) bits |= 4u;
                if (id >= 4 && jd >= 4) bits |= 8u;
            }
            pm[slot >> 3] |= bits << ((slot & 7) * 4);
        }

    int rbase[6];
    #pragma unroll
    for (int mt = 0; mt < 6; ++mt) {
        const int p = mt * 16 + cl;
        const int ia = p / 9, ja = p - 9 * ia;
        rbase[mt] = (p < 81) ? (ia * 10 + ja) : 0;
    }

    {
        ushort8 z8 = {0,0,0,0,0,0,0,0};
        for (int r = lane; r < 100; r += 64) {
            const int pi = r / 10, pj = r - 10 * (r / 10);
            if (pi == 0 || pi == 9 || pj == 0 || pj == 9) {
                *reinterpret_cast<ushort8*>(&hT[wave][r][0])  = z8;
                *reinterpret_cast<ushort8*>(&hT[wave][r][8])  = z8;
                *reinterpret_cast<ushort8*>(&hT[wave][r][16]) = z8;
                *reinterpret_cast<ushort8*>(&hT[wave][r][24]) = z8;
                xs[wave][r] = 0.0f;
            }
        }
    }
    __syncthreads();   // w1t ready (once)

    const int i = lane >> 3, j = lane & 7;
    const int rr = (i + 1) * 10 + (j + 1);
    const int gw = blockIdx.x * 4 + wave;
    const int nw = gridDim.x * 4;

    float v = (gw < n) ? x[(size_t)gw * 64 + lane] : 0.0f;

    for (int node = gw; node < n; node += nw) {
        #pragma unroll
        for (int ct = 0; ct < 4; ++ct)
            #pragma unroll
            for (int tap = 0; tap < 4; ++tap) {
                f32x4 tmp = __builtin_bit_cast(f32x4, bfr[ct][tap]);
                asm volatile("" : "+v"(tmp));
                bfr[ct][tap] = __builtin_bit_cast(bf16x8, tmp);
            }

        const int nn = node + nw;
        const float vnext = x[(size_t)(nn < n ? nn : node) * 64 + lane];

        xs[wave][rr] = v;
        asm volatile("s_waitcnt lgkmcnt(0)" ::: "memory");

        float xv[9];
        #pragma unroll
        for (int ki = 0; ki < 3; ++ki)
            #pragma unroll
            for (int kj = 0; kj < 3; ++kj)
                xv[ki * 3 + kj] = xs[wave][(i + ki) * 10 + (j + kj)];

        #pragma unroll
        for (int cp = 0; cp < 4; ++cp) {
            ushort8 hv;
            #pragma unroll
            for (int half = 0; half < 2; ++half) {
                const int cg2 = cp * 2 + half;
                f32x4 s = *reinterpret_cast<const f32x4*>(&w1t[9][cg2 * 4]);
                #pragma unroll
                for (int q = 0; q < 9; ++q) {
                    const f32x4 wq = *reinterpret_cast<const f32x4*>(&w1t[q][cg2 * 4]);
                    s += xv[q] * wq;
                }
                #pragma unroll
                for (int c = 0; c < 4; ++c)
                    hv[half * 4 + c] = bfbits(fmaxf(s[c], 0.0f));
            }
            *reinterpret_cast<ushort8*>(&hT[wave][rr][cp * 8]) = hv;
        }
        asm volatile("s_waitcnt lgkmcnt(0)" ::: "memory");

        f32x2 pb01[4], pb23[4];
        #pragma unroll
        for (int ct = 0; ct < 4; ++ct) { pb01[ct] = (f32x2){0.f,0.f}; pb23[ct] = (f32x2){0.f,0.f}; }

        #pragma unroll
        for (int mt = 0; mt < 6; ++mt) {
            const int rb = rbase[mt];
            bf16x8 a[4];
            a[0] = *reinterpret_cast<const bf16x8*>(&hT[wave][rb][kg * 8]);
            a[1] = *reinterpret_cast<const bf16x8*>(&hT[wave][rb + 1][kg * 8]);
            a[2] = *reinterpret_cast<const bf16x8*>(&hT[wave][rb + 10][kg * 8]);
            a[3] = *reinterpret_cast<const bf16x8*>(&hT[wave][rb + 11][kg * 8]);

            f32x4 acc[4];
            #pragma unroll
            for (int ct = 0; ct < 4; ++ct)
                acc[ct] = (f32x4){b2r[ct], b2r[ct], b2r[ct], b2r[ct]};
            #pragma unroll
            for (int tap = 0; tap < 4; ++tap)
                #pragma unroll
                for (int ct = 0; ct < 4; ++ct)
                    acc[ct] = __builtin_amdgcn_mfma_f32_16x16x32_bf16(a[tap], bfr[ct][tap], acc[ct], 0, 0, 0);

            #pragma unroll
            for (int rg = 0; rg < 4; ++rg) {
                if (mt * 16 + rg >= 81) continue;
                const int slot = mt * 4 + rg;
                const unsigned int bits = pm[slot >> 3] >> ((slot & 7) * 4);
                const f32x2 w01 = {(float)(bits & 1u), (float)((bits >> 1) & 1u)};
                const f32x2 w23 = {(float)((bits >> 2) & 1u), (float)((bits >> 3) & 1u)};
                #pragma unroll
                for (int ct = 0; ct < 4; ++ct) {
                    const float vr = fmaxf(acc[ct][rg], 0.0f);
                    const f32x2 v2 = {vr, vr};
                    pb01[ct] += v2 * w01;
                    pb23[ct] += v2 * w23;
                }
            }
        }

        const bool k0 = (kg & 1) != 0;
        const bool k1 = (kg & 2) != 0;
        float outb[4];
        #pragma unroll
        for (int b = 0; b < 4; ++b) {
            const float x0 = (b < 2) ? pb01[0][b] : pb23[0][b - 2];
            const float x1 = (b < 2) ? pb01[1][b] : pb23[1][b - 2];
            const float x2 = (b < 2) ? pb01[2][b] : pb23[2][b - 2];
            const float x3 = (b < 2) ? pb01[3][b] : pb23[3][b - 2];
            float keepA = k0 ? x1 : x0, sendA = k0 ? x0 : x1;
            float keepB = k0 ? x3 : x2, sendB = k0 ? x2 : x3;
            keepA += __shfl_xor(sendA, 16);
            keepB += __shfl_xor(sendB, 16);
            float keep = k1 ? keepB : keepA, send = k1 ? keepA : keepB;
            keep += __shfl_xor(send, 32);
            outb[b] = keep;
        }
        ushort4v pv;
        #pragma unroll
        for (int b = 0; b < 4; ++b) pv[b] = bfbits(outb[b]);
        *reinterpret_cast<ushort4v*>(poolbf + (size_t)node * 256 + lane * 4) = pv;

        v = vnext;
    }
}

// ---------------------------------------------------------------------------
// precount: blocks [0,80) = weight precompute; blocks [80,..) = degree count.
// ---------------------------------------------------------------------------
__global__ void precount_k(const float* __restrict__ fw, const float* __restrict__ fb,
                           const float* __restrict__ g1w, const float* __restrict__ g2w,
                           unsigned short* __restrict__ W1t, float* __restrict__ v1,
                           unsigned short* __restrict__ W2t,
                           const int* __restrict__ ei, float* __restrict__ outdeg,
                           float* __restrict__ indeg, int m)
{
    const int b = blockIdx.x, t = threadIdx.x;
    if (b < 64) {
        float s = 0.0f;
        for (int jj = 0; jj < 32; ++jj) s += fw[t * 32 + jj] * g1w[jj * 64 + b];
        W1t[b * 256 + t] = bfbits(0.04f * s);
    } else if (b < 80) {
        const int idx = (b - 64) * 256 + t;
        const int nc = idx >> 6, k = idx & 63;
        W2t[nc * 64 + k] = bfbits(g2w[k * 64 + nc]);
        if (b == 64 && t < 64) {
            float s = 0.0f;
            for (int jj = 0; jj < 32; ++jj) s += fb[jj] * g1w[jj * 64 + t];
            v1[t] = s;
        }
    } else {
        const int e = (b - 80) * 256 + t;
        if (e >= m) return;
        atomicAdd(&outdeg[ei[e]], 1.0f);
        atomicAdd(&indeg[ei[m + e]], 1.0f);
    }
}

// ---------------------------------------------------------------------------
// mm1att: blocks [0,gmm) = h = pool @ W1t (+v1), zero acc rows when separate;
//         blocks [gmm,..) = attprep (dis + att1 + att2).
// ---------------------------------------------------------------------------
template<bool ZEROACC>
__global__ __launch_bounds__(256) void mm1att_k(
    const unsigned short* __restrict__ A, const unsigned short* __restrict__ Bt,
    const float* __restrict__ v1, float* __restrict__ h, float* __restrict__ acc,
    const float* __restrict__ aux, const int* __restrict__ ei,
    const float* __restrict__ outdeg, const float* __restrict__ indeg,
    float* __restrict__ dis, float* __restrict__ att1, float* __restrict__ att2,
    int n, int m, int gmm)
{
    const int t = threadIdx.x;
    if ((int)blockIdx.x >= gmm) {
        const int e = (blockIdx.x - gmm) * 256 + t;
        if (e < n) dis[e] = rsqrtf(indeg[e] + 1.0f);
        if (e >= m) return;
        const int s = ei[e], d = ei[m + e];
        const float fs = aux[(size_t)s * 3 + 2], fdd = aux[(size_t)d * 3 + 2];
        const float fd = fabsf(fs - fdd);
        att1[e] = (fd == 1.0f) ? (1.0f / fmaxf(outdeg[s], 1.0f)) : 0.0f;
        const float angs = aux[(size_t)s * 3 + 0], rads = aux[(size_t)s * 3 + 1];
        const float angd = aux[(size_t)d * 3 + 0], radd = aux[(size_t)d * 3 + 1];
        const float dx = radd * cosf(angd) - rads * cosf(angs);
        const float dy = radd * sinf(angd) - rads * sinf(angs);
        const float vel = sqrtf(dx * dx + dy * dy + 1e-12f) * 0.5f;
        att2[e] = (fd == 2.0f) ? expf(-vel / 8.5f) : 0.0f;
        return;
    }

    const int lane = t & 63;
    const int cl = lane & 15, kg = lane >> 4;
    const int gw = blockIdx.x * 4 + (t >> 6);
    const int nw = gmm * 4;
    const int ntiles = (n + 15) >> 4;

    float vv[4];
    #pragma unroll
    for (int nt = 0; nt < 4; ++nt) vv[nt] = v1[nt * 16 + cl];

    for (int mt = gw; mt < ntiles; mt += nw) {
        const int r = min(mt * 16 + cl, n - 1);
        const unsigned short* ar = A + (size_t)r * 256 + kg * 8;
        f32x4 accf[4];
        #pragma unroll
        for (int nt = 0; nt < 4; ++nt)
            accf[nt] = (f32x4){vv[nt], vv[nt], vv[nt], vv[nt]};
        #pragma unroll
        for (int ks = 0; ks < 8; ++ks) {
            const bf16x8 afr = *reinterpret_cast<const bf16x8*>(ar + ks * 32);
            #pragma unroll
            for (int nt = 0; nt < 4; ++nt) {
                const bf16x8 bfrg = *reinterpret_cast<const bf16x8*>(
                    Bt + (size_t)(nt * 16 + cl) * 256 + ks * 32 + kg * 8);
                accf[nt] = __builtin_amdgcn_mfma_f32_16x16x32_bf16(afr, bfrg, accf[nt], 0, 0, 0);
            }
        }
        #pragma unroll
        for (int nt = 0; nt < 4; ++nt)
            #pragma unroll
            for (int rg = 0; rg < 4; ++rg) {
                const int row = mt * 16 + (kg << 2) + rg;
                if (row < n) h[(size_t)row * 64 + nt * 16 + cl] = accf[nt][rg];
            }
        if (ZEROACC) {
            const int zr = mt * 16 + cl;
            if (zr < n) {
                const f32x4 z = {0.f, 0.f, 0.f, 0.f};
                float* zp = acc + (size_t)zr * 64 + kg * 16;
                *reinterpret_cast<f32x4*>(zp)      = z;
                *reinterpret_cast<f32x4*>(zp + 4)  = z;
                *reinterpret_cast<f32x4*>(zp + 8)  = z;
                *reinterpret_cast<f32x4*>(zp + 12) = z;
            }
        }
    }
}

// ---------------------------------------------------------------------------
// mm2f: fused fin1 + GCN-2 matmul; zeroes acc rows after reading them.
// att1[r]==0 -> x1 row exactly 0: skip acc/h loads (exec-masked, 82% of rows).
// ---------------------------------------------------------------------------
template<bool ZEROACC>
__global__ __launch_bounds__(256) void mm2f_k(
    const float* __restrict__ acc, const float* __restrict__ hin,
    const float* __restrict__ dis, const float* __restrict__ g1b,
    const float* __restrict__ att1, const unsigned short* __restrict__ Bt,
    float* __restrict__ hout, float* __restrict__ accz, int n)
{
    const int lane = threadIdx.x & 63;
    const int cl = lane & 15, kg = lane >> 4;
    const int gw = blockIdx.x * 4 + (threadIdx.x >> 6);
    const int nw = gridDim.x * 4;
    const int ntiles = (n + 15) >> 4;

    for (int mt = gw; mt < ntiles; mt += nw) {
        const int r = min(mt * 16 + cl, n - 1);
        const float at = att1[r];
        f32x4 accf[4];
        #pragma unroll
        for (int nt = 0; nt < 4; ++nt) accf[nt] = (f32x4){0.f, 0.f, 0.f, 0.f};
        #pragma unroll
        for (int ks = 0; ks < 2; ++ks) {
            if (ZEROACC) {
                const f32x4 z = {0.f, 0.f, 0.f, 0.f};
                float* zp = accz + (size_t)r * 64 + ks * 32 + kg * 8;
                *reinterpret_cast<f32x4*>(zp)     = z;
                *reinterpret_cast<f32x4*>(zp + 4) = z;
            }
            ushort8 u = {0, 0, 0, 0, 0, 0, 0, 0};
            if (at != 0.0f) {
                const float di = dis[r];
                const float di2 = di * di;
                const float* ap = acc + (size_t)r * 64 + ks * 32 + kg * 8;
                const float* hp = hin + (size_t)r * 64 + ks * 32 + kg * 8;
                const float* bp = g1b + ks * 32 + kg * 8;
                #pragma unroll
                for (int e = 0; e < 8; ++e)
                    u[e] = bfbits(fmaxf((ap[e] + bp[e] + di2 * hp[e]) * at, 0.0f));
            }
            const bf16x8 afr = __builtin_bit_cast(bf16x8, u);
            #pragma unroll
            for (int nt = 0; nt < 4; ++nt) {
                const bf16x8 bfrg = *reinterpret_cast<const bf16x8*>(
                    Bt + (size_t)(nt * 16 + cl) * 64 + ks * 32 + kg * 8);
                accf[nt] = __builtin_amdgcn_mfma_f32_16x16x32_bf16(afr, bfrg, accf[nt], 0, 0, 0);
            }
        }
        #pragma unroll
        for (int nt = 0; nt < 4; ++nt)
            #pragma unroll
            for (int rg = 0; rg < 4; ++rg) {
                const int row = mt * 16 + (kg << 2) + rg;
                if (row < n) hout[(size_t)row * 64 + nt * 16 + cl] = accf[nt][rg];
            }
    }
}

// ---------------------------------------------------------------------------
// scatter with exact-zero skip (wave-uniform early exit).
// ---------------------------------------------------------------------------
template<bool HAS_S>
__global__ void scatter_k(const float* __restrict__ h, const int* __restrict__ ei,
                          const float* __restrict__ dis,
                          const float* __restrict__ skd, const float* __restrict__ sks,
                          float* __restrict__ acc, int m)
{
    size_t idx = (size_t)blockIdx.x * blockDim.x + threadIdx.x;
    if (idx >= (size_t)m * 64) return;
    const int e = (int)(idx >> 6), k = (int)(idx & 63);
    const int s = ei[e], d = ei[m + e];
    if (skd[d] == 0.0f) return;
    if (HAS_S && sks[s] == 0.0f) return;
    const float w = dis[s] * dis[d];
    atomicAdd(&acc[(size_t)d * 64 + k], w * h[(size_t)s * 64 + k]);
}

// ---------------------------------------------------------------------------
// finhead: fin2 into LDS (skip loads when att2==0: exact-0 row), then head.
// ---------------------------------------------------------------------------
__global__ __launch_bounds__(256) void finhead_k(
    const float* __restrict__ acc, const float* __restrict__ h,
    const float* __restrict__ dis, const float* __restrict__ g2b,
    const float* __restrict__ att2,
    const float* __restrict__ fcw, const float* __restrict__ fcb,
    const float* __restrict__ outw, const float* __restrict__ outb,
    float* __restrict__ out, int n)
{
    __shared__ float sm[8][64];
    const int t = threadIdx.x;
    const int nb = blockIdx.x * 8;

    #pragma unroll
    for (int pp = 0; pp < 2; ++pp) {
        const int p = t + pp * 256;
        const int nd = p >> 6, k = p & 63;
        const int node = nb + nd;
        if (node < n) {
            const float a2 = att2[node];
            float val = 0.0f;
            if (a2 != 0.0f) {
                const float di = dis[node];
                const size_t idx = (size_t)node * 64 + k;
                val = fmaxf((acc[idx] + g2b[k] + di * di * h[idx]) * a2, 0.0f);
            }
            sm[nd][k] = val;
        }
    }
    __syncthreads();

    const int nd = t >> 5, o = t & 31;
    const int node = nb + nd;
    if (node >= n) return;
    float s = fcb[o];
    #pragma unroll
    for (int k = 0; k < 64; ++k) s = fmaf(sm[nd][k], fcw[k * 32 + o], s);
    s = fmaxf(s, 0.0f);
    float p = s * outw[o];
    #pragma unroll
    for (int mk = 16; mk >= 1; mk >>= 1) p += __shfl_xor(p, mk);
    if (o == 0) out[node] = 1.0f / (1.0f + expf(-(p + outb[0])));
}

// ---------------------------------------------------------------------------
extern "C" void kernel_launch(void* const* d_in, const int* in_sizes, int n_in,
                              void* d_out, int out_size, void* d_ws, size_t ws_size,
                              hipStream_t stream)
{
    const float* x    = (const float*)d_in[0];
    const float* aux  = (const float*)d_in[1];
    const int*   ei   = (const int*)  d_in[2];
    const float* c1w  = (const float*)d_in[3];
    const float* c1b  = (const float*)d_in[4];
    const float* c2w  = (const float*)d_in[5];
    const float* c2b  = (const float*)d_in[6];
    const float* few  = (const float*)d_in[7];
    const float* feb  = (const float*)d_in[8];
    const float* g1w  = (const float*)d_in[9];
    const float* g1b  = (const float*)d_in[10];
    const float* g2w  = (const float*)d_in[11];
    const float* g2b  = (const float*)d_in[12];
    const float* fcw  = (const float*)d_in[13];
    const float* fcb  = (const float*)d_in[14];
    const float* outw = (const float*)d_in[15];
    const float* outb = (const float*)d_in[16];
    float* out = (float*)d_out;

    const int n = in_sizes[0] / 64;       // nodes
    const int m = in_sizes[2] / 2;        // edges

    float* ws = (float*)d_ws;
    const size_t tailf = 8192 + 64 + 2048 + 320 + (size_t)3 * n + (size_t)2 * m;
    const bool sep = ws_size >= ((size_t)n * 256 + tailf) * sizeof(float);

    unsigned short* poolbf = (unsigned short*)ws;
    float* h;
    float* acc;
    float* wtail;
    if (sep) {
        h     = ws + (size_t)n * 128;
        acc   = ws + (size_t)n * 192;
        wtail = ws + (size_t)n * 256;
    } else {
        acc   = ws;
        h     = ws + (size_t)n * 128;
        wtail = ws + (size_t)n * 192;
    }
    unsigned short* W1t = (unsigned short*)wtail;
    float* v1   = wtail + 8192;
    unsigned short* W2t = (unsigned short*)(v1 + 64);
    float* pad    = v1 + 64 + 2048;      // 320 floats reserved (layout stable)
    float* outdeg = pad + 320;
    float* indeg  = outdeg + n;
    float* dis    = indeg + n;
    float* att1   = dis + n;
    float* att2   = att1 + m;

    const dim3 b256(256);
    const int gE   = (m + 255) / 256;
    const int gNE  = (max(n, m) + 255) / 256;
    const int gEM  = (int)(((size_t)m * 64 + 255) / 256);
    const int gMM  = (((n + 15) / 16) + 3) / 4;

    hipMemsetAsync(outdeg, 0, (size_t)2 * n * sizeof(float), stream);
    precount_k<<<80 + gE, b256, 0, stream>>>(few, feb, g1w, g2w,
                                             W1t, v1, W2t, ei, outdeg, indeg, m);
    fe_kernel<<<768, b256, 0, stream>>>(x, c1w, c1b, c2w, c2b, poolbf, n);

    if (sep) {
        mm1att_k<true><<<gMM + gNE, b256, 0, stream>>>(poolbf, W1t, v1, h, acc,
            aux, ei, outdeg, indeg, dis, att1, att2, n, m, gMM);
    } else {
        mm1att_k<false><<<gMM + gNE, b256, 0, stream>>>(poolbf, W1t, v1, h, acc,
            aux, ei, outdeg, indeg, dis, att1, att2, n, m, gMM);
        hipMemsetAsync(acc, 0, (size_t)n * 64 * sizeof(float), stream);
    }
    // layer-1 scatter: dead if att1[dst]==0
    scatter_k<false><<<gEM, b256, 0, stream>>>(h, ei, dis, att1, nullptr, acc, m);

    mm2f_k<true><<<gMM, b256, 0, stream>>>(acc, h, dis, g1b, att1, W2t, h, acc, n);
    // layer-2 scatter: dead if att2[dst]==0 or h2[src] row exactly zero
    scatter_k<true><<<gEM, b256, 0, stream>>>(h, ei, dis, att2, att1, acc, m);

    finhead_k<<<(n + 7) / 8, b256, 0, stream>>>(acc, h, dis, g2b, att2,
                                                fcw, fcb, outw, outb, out, n);
}